// Round 1
// baseline (94.766 us; speedup 1.0000x reference)
//
#include <hip/hip_runtime.h>
#include <math.h>

// out[b,s,n] = sum_e SIN_TABLE[idx(w[e,n]*x[b,s,e] + b[e,n] + t[s])]
// B=2, S=1024, E=128, N=512. LUT_RES=512.
// SIN_TABLE[i] = sin(i * 2pi/512)  -> computed via v_sin_f32 (revolutions input).

constexpr int E_DIM = 128;
constexpr int N_DIM = 512;
constexpr int ST    = 4;     // s-rows per block

__global__ __launch_bounds__(512) void sin_layer_kernel(
    const float* __restrict__ x,    // (B,S,E)
    const float* __restrict__ w,    // (E,N)
    const float* __restrict__ bv_,  // (E,N)
    const float* __restrict__ t,    // (S)
    float* __restrict__ out,        // (B,S,N)
    int S)
{
    const int n   = threadIdx.x;          // one n per thread, 0..511
    const int bs0 = blockIdx.x * ST;      // first flattened (b*S + s) row

    // Reference constants, matching jnp fp32 exactly:
    constexpr float TWO_PI_F = 6.2831854820251465f;   // fl32(2*pi)
    constexpr float INV2PI   = 0.15915493667125702f;  // fl32(1.0/(2*pi double))
    constexpr float SCALE    = 512.0f * INV2PI;       // exact (exponent shift)
    constexpr float INV512   = 1.0f / 512.0f;

    float acc[ST];
    float ts[ST];
    const float* xrow[ST];
#pragma unroll
    for (int i = 0; i < ST; ++i) {
        acc[i] = 0.0f;
        int bs = bs0 + i;
        int s  = (bs >= S) ? (bs - S) : bs;   // bs < 2*S
        ts[i]  = t[s];
        xrow[i] = x + (size_t)bs * E_DIM;
    }

#pragma unroll 4
    for (int e = 0; e < E_DIM; ++e) {
        const float wv = w[e * N_DIM + n];
        const float bb = bv_[e * N_DIM + n];
#pragma unroll
        for (int i = 0; i < ST; ++i) {
            const float xv = xrow[i][e];   // wave-uniform -> scalar load
            // phase = ((w*x) + b) + t  (separate roundings, like reference)
            float p = __fadd_rn(__fadd_rn(__fmul_rn(wv, xv), bb), ts[i]);
            // m = fmod(p, 2pi) in [0, 2pi): single-rounding residual via FMA
            float u = p * INV2PI;
            float q = floorf(u);
            float m = __fmaf_rn(-q, TWO_PI_F, p);
            // bin = trunc(m * (512/2pi))  == trunc((m*INV2PI)*512) bitwise
            float fi   = m * SCALE;
            float fbin = truncf(fi);          // >= 0 (rare -0 edge: sin(0)=0)
            float rev  = fbin * INV512;       // revolutions in [0,1]
            acc[i] += __builtin_amdgcn_sinf(rev);   // v_sin_f32: sin(2pi*rev)
        }
    }

#pragma unroll
    for (int i = 0; i < ST; ++i) {
        out[(size_t)(bs0 + i) * N_DIM + n] = acc[i];
    }
}

extern "C" void kernel_launch(void* const* d_in, const int* in_sizes, int n_in,
                              void* d_out, int out_size, void* d_ws, size_t ws_size,
                              hipStream_t stream) {
    const float* x = (const float*)d_in[0];   // (B,S,E)
    const float* w = (const float*)d_in[1];   // (E,N)
    const float* b = (const float*)d_in[2];   // (E,N)
    const float* t = (const float*)d_in[3];   // (S)
    float* out = (float*)d_out;               // (B,S,N)

    const int S  = in_sizes[3];               // 1024
    const int BS = in_sizes[0] / E_DIM;       // B*S = 2048

    const int grid = BS / ST;                 // 512 blocks
    sin_layer_kernel<<<grid, N_DIM, 0, stream>>>(x, w, b, t, out, S);
}

// Round 2
// 91.645 us; speedup vs baseline: 1.0341x; 1.0341x over previous
//
#include <hip/hip_runtime.h>
#include <math.h>

// out[b,s,n] = sum_e SIN_TABLE[idx(w[e,n]*x[b,s,e] + b[e,n] + t[s])]
// B=2, S=1024, E=128, N=512, LUT_RES=512.
// Scaled-phase formulation: u = (w*x + b + t) / 2pi (revolutions), computed as
// fma(w*INV2PI, x, b*INV2PI + t*INV2PI). fract(u) is exact (Sterbenz), then
// floor-bin to 512 levels and v_sin_f32 (input in revolutions).

constexpr int E_DIM = 128;
constexpr int N_DIM = 512;
constexpr int ST    = 2;     // s-rows per block
constexpr int TPB   = 256;   // threads per block = n-half

__global__ __launch_bounds__(TPB) void sin_layer_kernel(
    const float* __restrict__ x,    // (B,S,E)
    const float* __restrict__ w,    // (E,N)
    const float* __restrict__ bv_,  // (E,N)
    const float* __restrict__ t,    // (S)
    float* __restrict__ out,        // (B,S,N)
    int S)
{
    constexpr float INV2PI = 0.15915493667125702f;  // fl32(1/(2*pi))
    constexpr float INV512 = 1.0f / 512.0f;

    const int nh  = blockIdx.x & 1;        // which n-half
    const int g   = blockIdx.x >> 1;       // row group
    const int n   = nh * TPB + threadIdx.x;
    const int bs0 = g * ST;

    float tn[ST];
    float acc[ST];
    const float* xrow[ST];
#pragma unroll
    for (int i = 0; i < ST; ++i) {
        const int bs = bs0 + i;
        const int s  = bs % S;
        tn[i]  = t[s] * INV2PI;            // t in revolutions (per-row, hoisted)
        xrow[i] = x + (size_t)bs * E_DIM;
        acc[i] = 0.0f;
    }

    const float* wp = w   + n;
    const float* bp = bv_ + n;

#pragma unroll 4
    for (int e = 0; e < E_DIM; ++e) {
        const float wn = wp[(size_t)e * N_DIM] * INV2PI;   // w in rev units
        const float bn = bp[(size_t)e * N_DIM] * INV2PI;   // b in rev units
#pragma unroll
        for (int i = 0; i < ST; ++i) {
            const float xv = xrow[i][e];                   // wave-uniform -> s_load
            float u = __fmaf_rn(wn, xv, bn + tn[i]);       // phase in revolutions
            float f = __builtin_amdgcn_fractf(u);          // in [0,1), exact
            float k = floorf(f * 512.0f);                  // LUT bin (f*512 exact)
            acc[i] += __builtin_amdgcn_sinf(k * INV512);   // sin(2pi * k/512)
        }
    }

#pragma unroll
    for (int i = 0; i < ST; ++i) {
        out[(size_t)(bs0 + i) * N_DIM + n] = acc[i];
    }
}

extern "C" void kernel_launch(void* const* d_in, const int* in_sizes, int n_in,
                              void* d_out, int out_size, void* d_ws, size_t ws_size,
                              hipStream_t stream) {
    const float* x = (const float*)d_in[0];   // (B,S,E)
    const float* w = (const float*)d_in[1];   // (E,N)
    const float* b = (const float*)d_in[2];   // (E,N)
    const float* t = (const float*)d_in[3];   // (S)
    float* out = (float*)d_out;               // (B,S,N)

    const int S  = in_sizes[3];               // 1024
    const int BS = in_sizes[0] / E_DIM;       // B*S = 2048

    const int grid = (BS / ST) * (N_DIM / TPB);  // 1024 * 2 = 2048 blocks
    sin_layer_kernel<<<grid, TPB, 0, stream>>>(x, w, b, t, out, S);
}

// Round 3
// 88.068 us; speedup vs baseline: 1.0761x; 1.0406x over previous
//
#include <hip/hip_runtime.h>
#include <math.h>

// out[b,s,n] = sum_e SIN_TABLE[idx(w[e,n]*x[b,s,e] + b[e,n] + t[s])]
// B=2, S=1024, E=128, N=512, LUT_RES=512.
//
// Bin-unit formulation: prescale w,b,t by SCALE = fl32(1/2pi)*512 so the
// phase is directly in LUT-bin units. Then per element:
//   u  = fma(wn, x, btn)        (bin-scaled phase, |u| <= ~84k)
//   k  = floorf(u)              (bin index, negative ok)
//   acc += v_sin(k * (1/512))   (sin takes revolutions; |arg|<=165 < 256
//                                valid range; periodicity == the %512)
// 4 VALU + 1 trans per element; ST=8 rows amortize loads + prescale.

constexpr int E_DIM = 128;
constexpr int N_DIM = 512;
constexpr int ST    = 8;     // s-rows per block
constexpr int TPB   = 256;   // threads per block (n-half)

__global__ __launch_bounds__(TPB) void sin_layer_kernel(
    const float* __restrict__ x,    // (B,S,E)
    const float* __restrict__ w,    // (E,N)
    const float* __restrict__ bv_,  // (E,N)
    const float* __restrict__ t,    // (S)
    float* __restrict__ out,        // (B,S,N)
    int S)
{
    // 512 * fl32(1/(2*pi)) — matches reference's (frac*INV2PI)*512 scale exactly
    constexpr float SCALE  = 512.0f * 0.15915493667125702f;
    constexpr float INV512 = 1.0f / 512.0f;

    const int nh  = blockIdx.x & 1;        // n-half
    const int g   = blockIdx.x >> 1;       // row group
    const int n   = nh * TPB + threadIdx.x;
    const int bs0 = g * ST;

    float tn[ST];                           // wave-uniform -> SGPRs
    float acc[ST];
    const float* xr[ST];
#pragma unroll
    for (int i = 0; i < ST; ++i) {
        const int bs = bs0 + i;
        const int s  = (bs >= S) ? (bs - S) : bs;
        tn[i]  = t[s] * SCALE;              // t in bin units
        xr[i]  = x + (size_t)bs * E_DIM;
        acc[i] = 0.0f;
    }

    const float* wp = w   + n;
    const float* bp = bv_ + n;

#pragma unroll 4
    for (int e = 0; e < E_DIM; ++e) {
        const float wv = wp[(size_t)e * N_DIM];
        const float bv = bp[(size_t)e * N_DIM];
        const float wn = wv * SCALE;        // w in bin units
        float btn[ST];
#pragma unroll
        for (int i = 0; i < ST; ++i)
            btn[i] = __fmaf_rn(bv, SCALE, tn[i]);   // (b + t) in bin units
#pragma unroll
        for (int i = 0; i < ST; ++i) {
            const float xv = xr[i][e];               // wave-uniform -> s_load
            float u = __fmaf_rn(wn, xv, btn[i]);     // bin-scaled phase
            float k = floorf(u);                     // LUT bin (sign ok)
            acc[i] += __builtin_amdgcn_sinf(k * INV512);
        }
    }

#pragma unroll
    for (int i = 0; i < ST; ++i) {
        out[(size_t)(bs0 + i) * N_DIM + n] = acc[i];
    }
}

extern "C" void kernel_launch(void* const* d_in, const int* in_sizes, int n_in,
                              void* d_out, int out_size, void* d_ws, size_t ws_size,
                              hipStream_t stream) {
    const float* x = (const float*)d_in[0];   // (B,S,E)
    const float* w = (const float*)d_in[1];   // (E,N)
    const float* b = (const float*)d_in[2];   // (E,N)
    const float* t = (const float*)d_in[3];   // (S)
    float* out = (float*)d_out;               // (B,S,N)

    const int S  = in_sizes[3];               // 1024
    const int BS = in_sizes[0] / E_DIM;       // B*S = 2048

    const int grid = (BS / ST) * (N_DIM / TPB);   // 256 * 2 = 512 blocks
    sin_layer_kernel<<<grid, TPB, 0, stream>>>(x, w, b, t, out, S);
}